// Round 17
// baseline (311.066 us; speedup 1.0000x reference)
//
#include <hip/hip_runtime.h>
#include <hip/hip_bf16.h>

typedef __attribute__((ext_vector_type(8))) short short8;
typedef __attribute__((ext_vector_type(8))) _Float16 half8;
typedef __attribute__((ext_vector_type(4))) float f32x4;

__device__ __forceinline__ unsigned short f2h(float f) {
    _Float16 h = (_Float16)f;
    return *reinterpret_cast<unsigned short*>(&h);
}
__device__ __forceinline__ float h2f(unsigned short u) {
    _Float16 h = *reinterpret_cast<_Float16*>(&u);
    return (float)h;
}

// async global->LDS, 16B per lane, wave-uniform LDS base + lane*16 dest
__device__ __forceinline__ void gld_lds16(const unsigned short* g, unsigned short* l) {
    __builtin_amdgcn_global_load_lds(
        (const __attribute__((address_space(1))) unsigned int*)g,
        (__attribute__((address_space(3))) unsigned int*)l, 16, 0, 0);
}

// ---------------- fused weight transpose + fp16 convert (one launch) ----------------
__global__ __launch_bounds__(256)
void transpose_all(const float* __restrict__ W0, const float* __restrict__ W1,
                   const float* __restrict__ W2, const float* __restrict__ W3,
                   unsigned short* __restrict__ o0, unsigned short* __restrict__ o1,
                   unsigned short* __restrict__ o2, unsigned short* __restrict__ o3) {
    __shared__ float tile[32][33];
    const int bid = blockIdx.x;
    const float* W; unsigned short* out; int K, N, loc;
    if (bid < 3072)      { W = W0; out = o0; K = 1024; N = 3072; loc = bid; }
    else if (bid < 4096) { W = W1; out = o1; K = 1024; N = 1024; loc = bid - 3072; }
    else if (bid < 8192) { W = W2; out = o2; K = 1024; N = 4096; loc = bid - 4096; }
    else                 { W = W3; out = o3; K = 4096; N = 1024; loc = bid - 8192; }
    const int nx = N >> 5;
    const int n0 = (loc % nx) << 5, k0 = (loc / nx) << 5;
    const int tid = threadIdx.x;
    const int r = tid >> 3, c4 = (tid & 7) << 2;
    float4 v = *reinterpret_cast<const float4*>(W + (size_t)(k0 + r) * N + n0 + c4);
    tile[r][c4 + 0] = v.x; tile[r][c4 + 1] = v.y;
    tile[r][c4 + 2] = v.z; tile[r][c4 + 3] = v.w;
    __syncthreads();
    const int n = n0 + r;
    ushort4 o;
    o.x = f2h(tile[c4 + 0][r]); o.y = f2h(tile[c4 + 1][r]);
    o.z = f2h(tile[c4 + 2][r]); o.w = f2h(tile[c4 + 3][r]);
    *reinterpret_cast<ushort4*>(out + (size_t)n * K + k0 + c4) = o;
}

// ---------------- LayerNorm -> fp16 [row][1024]; input f32 (IN16=0) or fp16 (IN16=1)
template<int IN16>
__global__ __launch_bounds__(256)
void ln_kernel(const void* __restrict__ xin, const float* __restrict__ gw,
               const float* __restrict__ bw, unsigned short* __restrict__ out) {
    const int row = blockIdx.x, tid = threadIdx.x;
    float v0, v1, v2, v3;
    if (IN16) {
        const unsigned short* xr = (const unsigned short*)xin + (size_t)row * 1024;
        ushort4 u = *reinterpret_cast<const ushort4*>(xr + tid * 4);
        v0 = h2f(u.x); v1 = h2f(u.y); v2 = h2f(u.z); v3 = h2f(u.w);
    } else {
        const float* xr = (const float*)xin + (size_t)row * 1024;
        float4 v = *reinterpret_cast<const float4*>(xr + tid * 4);
        v0 = v.x; v1 = v.y; v2 = v.z; v3 = v.w;
    }
    float s = v0 + v1 + v2 + v3;
    float sq = v0 * v0 + v1 * v1 + v2 * v2 + v3 * v3;
    #pragma unroll
    for (int off = 1; off < 64; off <<= 1) {
        s  += __shfl_xor(s, off);
        sq += __shfl_xor(sq, off);
    }
    __shared__ float ps[4], pq[4];
    const int wave = tid >> 6;
    if ((tid & 63) == 0) { ps[wave] = s; pq[wave] = sq; }
    __syncthreads();
    s  = ps[0] + ps[1] + ps[2] + ps[3];
    sq = pq[0] + pq[1] + pq[2] + pq[3];
    const float mu = s * (1.0f / 1024.0f);
    const float var = sq * (1.0f / 1024.0f) - mu * mu;
    const float rs = rsqrtf(var + 1e-5f);
    float4 gv = *reinterpret_cast<const float4*>(gw + tid * 4);
    float4 bv = *reinterpret_cast<const float4*>(bw + tid * 4);
    ushort4 o;
    o.x = f2h((v0 - mu) * rs * gv.x + bv.x);
    o.y = f2h((v1 - mu) * rs * gv.y + bv.y);
    o.z = f2h((v2 - mu) * rs * gv.z + bv.z);
    o.w = f2h((v3 - mu) * rs * gv.w + bv.w);
    *reinterpret_cast<ushort4*>(out + (size_t)row * 1024 + tid * 4) = o;
}

// ---------------- mid-tile GEMM: 128x256, BK=32, 8 waves (2Mx4N), 48KB LDS ----------
// 2-phase prefetch; one barrier per K-tile; chunk-swizzled LDS (2-way conflicts, free).
// NZ==1: per-XCD contiguous bm stripes. NZ>1: xcd = bm%8, bn fastest.
// EPI 0: fp16 = acc+bias ; EPI 2: fp16 = gelu(acc+bias) ; EPI 4: fp16 raw partial
template<int EPI, int NZ>
__global__ __launch_bounds__(512, 4)
void gemm_mid(const unsigned short* __restrict__ A, const unsigned short* __restrict__ Bt,
              const float* __restrict__ bias, void* Cout,
              int M, int N, int K, int lda, int ldb, int ldc) {
    __shared__ unsigned short As[2][128 * 32];   // 8KB per buf
    __shared__ unsigned short Bs[2][256 * 32];   // 16KB per buf (total 48KB)
    const int tid = threadIdx.x;
    const int wave = tid >> 6, lane = tid & 63;
    const int nx = N >> 8;
    int bm, bn, z;
    if (NZ == 1) {
        const int nwg = gridDim.x;
        const int swz = (blockIdx.x & 7) * (nwg >> 3) + (blockIdx.x >> 3);
        bm = (swz / nx) << 7; bn = (swz % nx) << 8; z = 0;
    } else {
        int bid = blockIdx.x;
        const int xcd = bid & 7; int rest = bid >> 3;
        bn = (rest % nx) << 8; rest /= nx;
        z = rest % NZ; rest /= NZ;
        bm = (rest * 8 + xcd) << 7;              // requires (M/128) % 8 == 0
    }
    const size_t koff = (size_t)z * K;
    const int wm = wave >> 2, wn = wave & 3;     // 2 M-waves x 4 N-waves, 64x64 each
    const int fr = lane & 15, g8 = (lane >> 4) << 3, fq = (lane >> 4) << 2;
    const int jq = g8 >> 3;          // logical 16B chunk (0..3)
    const int sx2 = (fr >> 1) & 3;   // read-side XOR

    const int srow = lane >> 2;
    const int scol = ((lane & 3) ^ ((lane >> 3) & 3)) << 3;
    const unsigned short* gA  = A + (size_t)(bm + wave * 16 + srow) * lda + scol + koff;
    const unsigned short* gB0 = Bt + (size_t)(bn + wave * 32 + srow) * ldb + scol + koff;
    const unsigned short* gB1 = gB0 + (size_t)16 * ldb;
    const int lbA = wave * 512;      // wave-uniform LDS bases (shorts)
    const int lbB = wave * 1024;

    f32x4 acc[4][4];
    #pragma unroll
    for (int m = 0; m < 4; ++m)
        #pragma unroll
        for (int n_ = 0; n_ < 4; ++n_)
            #pragma unroll
            for (int r_ = 0; r_ < 4; ++r_) acc[m][n_][r_] = 0.0f;

    auto stage = [&](int buf, int k0) {
        gld_lds16(gA + k0, &As[buf][lbA]);
        gld_lds16(gB0 + k0, &Bs[buf][lbB]);
        gld_lds16(gB1 + k0, &Bs[buf][lbB + 512]);
    };
    auto compute = [&](int buf) {
        half8 af[4], bfv[4];
        #pragma unroll
        for (int m = 0; m < 4; ++m)
            af[m] = *reinterpret_cast<const half8*>(
                &As[buf][(wm * 64 + m * 16 + fr) * 32 + ((jq ^ sx2) << 3)]);
        #pragma unroll
        for (int n_ = 0; n_ < 4; ++n_)
            bfv[n_] = *reinterpret_cast<const half8*>(
                &Bs[buf][(wn * 64 + n_ * 16 + fr) * 32 + ((jq ^ sx2) << 3)]);
        #pragma unroll
        for (int m = 0; m < 4; ++m)
            #pragma unroll
            for (int n_ = 0; n_ < 4; ++n_)
                acc[m][n_] = __builtin_amdgcn_mfma_f32_16x16x32_f16(af[m], bfv[n_], acc[m][n_], 0, 0, 0);
    };

    const int nt = K >> 5;   // even for all our shapes
    stage(0, 0);
    __syncthreads();
    int k0 = 32;
    for (int t = 0; t < nt - 2; t += 2) {
        stage(1, k0);
        compute(0);
        __syncthreads();
        stage(0, k0 + 32);
        compute(1);
        __syncthreads();
        k0 += 64;
    }
    stage(1, k0);
    compute(0);
    __syncthreads();
    compute(1);

    if (EPI == 4) {
        unsigned short* P = reinterpret_cast<unsigned short*>(Cout) +
                            (size_t)z * (size_t)M * ldc;
        #pragma unroll
        for (int n_ = 0; n_ < 4; ++n_) {
            const int col = bn + wn * 64 + n_ * 16 + fr;
            #pragma unroll
            for (int m = 0; m < 4; ++m)
                #pragma unroll
                for (int r_ = 0; r_ < 4; ++r_) {
                    const int row = bm + wm * 64 + m * 16 + fq + r_;
                    P[(size_t)row * ldc + col] = f2h(acc[m][n_][r_]);
                }
        }
        return;
    }

    unsigned short* o16 = reinterpret_cast<unsigned short*>(Cout);
    #pragma unroll
    for (int n_ = 0; n_ < 4; ++n_) {
        const int col = bn + wn * 64 + n_ * 16 + fr;
        const float bc = bias[col];
        #pragma unroll
        for (int m = 0; m < 4; ++m) {
            #pragma unroll
            for (int r_ = 0; r_ < 4; ++r_) {
                const int row = bm + wm * 64 + m * 16 + fq + r_;
                const size_t idx = (size_t)row * ldc + col;
                float v = acc[m][n_][r_] + bc;
                if (EPI == 0) {
                    o16[idx] = f2h(v);
                } else {
                    float ge = 0.5f * v * (1.0f + erff(v * 0.70710678118654752f));
                    o16[idx] = f2h(ge);
                }
            }
        }
    }
}

// ---------------- 2-phase GEMM (skinny shapes), BK=32 chunk-swizzle -----------------
// REMAP=1: 1-D grid, xcd = bid&7 == bm%8, bn fastest within XCD.
// EPI 5: fp16 = acc + bias + resid(f32)   (x1h residual-out for proj)
template<int EPI, int BM, int REMAP>
__global__ __launch_bounds__(256)
void gemm_bt(const unsigned short* __restrict__ A, const unsigned short* __restrict__ Bt,
             const float* __restrict__ bias, const float* resid,
             void* Cout, int M, int N, int K, int lda, int ldb, int ldc) {
    constexpr int MF = BM / 32;
    __shared__ unsigned short As[2][BM * 32];
    __shared__ unsigned short Bs[2][128 * 32];
    const int tid = threadIdx.x;
    const int wave = tid >> 6, lane = tid & 63;
    int bm, bn;
    if (REMAP) {
        const int nxr = N >> 7;
        int bid = blockIdx.x;
        const int xcd = bid & 7; int rest = bid >> 3;
        bn = (rest % nxr) << 7; rest /= nxr;
        bm = (rest * 8 + xcd) * BM;              // requires (M/BM) % 8 == 0
    } else {
        bm = blockIdx.y * BM; bn = blockIdx.x << 7;
    }
    const int wr = (wave >> 1) * (BM / 2), wc = (wave & 1) << 6;
    const int fr = lane & 15, g8 = (lane >> 4) << 3, fq = (lane >> 4) << 2;
    const int jq = g8 >> 3, sx2 = (fr >> 1) & 3;

    const int srowA = (BM == 128) ? ((wave << 5) + (lane >> 2)) : ((wave << 4) + (lane >> 2));
    const int srowB = (wave << 5) + (lane >> 2);
    const int scol = (((lane & 3) ^ ((lane >> 3) & 3))) << 3;
    const unsigned short* gA0 = A + (size_t)(bm + srowA) * lda + scol;
    const unsigned short* gA1 = gA0 + (size_t)16 * lda;      // BM==128 only
    const unsigned short* gB0 = Bt + (size_t)(bn + srowB) * ldb + scol;
    const unsigned short* gB1 = gB0 + (size_t)16 * ldb;

    f32x4 acc[MF][4];
    #pragma unroll
    for (int m = 0; m < MF; ++m)
        #pragma unroll
        for (int n = 0; n < 4; ++n)
            #pragma unroll
            for (int r = 0; r < 4; ++r) acc[m][n][r] = 0.0f;

    auto stage = [&](int buf, int k0) {
        unsigned short* lA = &As[buf][(BM == 128) ? (wave << 10) : (wave << 9)];
        unsigned short* lB = &Bs[buf][wave << 10];
        gld_lds16(gA0 + k0, lA);
        if constexpr (BM == 128) gld_lds16(gA1 + k0, lA + 512);
        gld_lds16(gB0 + k0, lB);
        gld_lds16(gB1 + k0, lB + 512);
    };
    auto compute = [&](int buf) {
        half8 af[MF], bfv[4];
        #pragma unroll
        for (int m = 0; m < MF; ++m)
            af[m] = *reinterpret_cast<const half8*>(
                &As[buf][(wr + m * 16 + fr) * 32 + ((jq ^ sx2) << 3)]);
        #pragma unroll
        for (int n = 0; n < 4; ++n)
            bfv[n] = *reinterpret_cast<const half8*>(
                &Bs[buf][(wc + n * 16 + fr) * 32 + ((jq ^ sx2) << 3)]);
        #pragma unroll
        for (int m = 0; m < MF; ++m)
            #pragma unroll
            for (int n = 0; n < 4; ++n)
                acc[m][n] = __builtin_amdgcn_mfma_f32_16x16x32_f16(af[m], bfv[n], acc[m][n], 0, 0, 0);
    };

    const int nt = K >> 5;
    stage(0, 0);
    __syncthreads();
    int k0 = 32;
    for (int t = 0; t < nt - 2; t += 2) {
        stage(1, k0);
        compute(0);
        __syncthreads();
        stage(0, k0 + 32);
        compute(1);
        __syncthreads();
        k0 += 64;
    }
    stage(1, k0);
    compute(0);
    __syncthreads();
    compute(1);

    #pragma unroll
    for (int n = 0; n < 4; ++n) {
        const int col = bn + wc + n * 16 + fr;
        const float bc = bias[col];
        #pragma unroll
        for (int m = 0; m < MF; ++m) {
            #pragma unroll
            for (int r = 0; r < 4; ++r) {
                const int row = bm + wr + m * 16 + fq + r;
                const size_t idx = (size_t)row * ldc + col;
                float v = acc[m][n][r] + bc;
                // EPI 5: fp16 residual-out
                reinterpret_cast<unsigned short*>(Cout)[idx] = f2h(v + resid[idx]);
            }
        }
    }
}

// ---------------- split-K reduce: out(f32) = x1h(fp16) + bias + sum_z p[z](fp16) ----
template<int Z>
__global__ __launch_bounds__(256)
void red_h(const unsigned short* __restrict__ p, const unsigned short* __restrict__ x1h,
           const float* __restrict__ bias, float* out) {
    const size_t MN = (size_t)4096 * 1024;
    const size_t i = ((size_t)blockIdx.x * 256 + threadIdx.x) * 4;
    ushort4 xh = *reinterpret_cast<const ushort4*>(x1h + i);
    float4 bb = *reinterpret_cast<const float4*>(bias + (i & 1023));
    float o0 = h2f(xh.x) + bb.x, o1 = h2f(xh.y) + bb.y;
    float o2 = h2f(xh.z) + bb.z, o3 = h2f(xh.w) + bb.w;
    #pragma unroll
    for (int z = 0; z < Z; ++z) {
        ushort4 a = *reinterpret_cast<const ushort4*>(p + (size_t)z * MN + i);
        o0 += h2f(a.x); o1 += h2f(a.y); o2 += h2f(a.z); o3 += h2f(a.w);
    }
    float4 o; o.x = o0; o.y = o1; o.z = o2; o.w = o3;
    *reinterpret_cast<float4*>(out + i) = o;
}

// ---------------- K/V compaction ----------------
// K scaled by 8*log2(e): P = exp2(S - m) == exp((q.k)*8 - m'), one mul cheaper.
// Output layouts are EXACTLY the attn fragment read patterns (per-lane 16B rows).
__global__ __launch_bounds__(256)
void kv_conv(const unsigned short* __restrict__ qkv16, unsigned short* __restrict__ K_g,
             unsigned short* __restrict__ Vt_g) {
    __shared__ unsigned short VtT[64][72];
    const int kc = blockIdx.x;
    const int bh = blockIdx.y;
    const int b = bh >> 4, h = bh & 15;
    const int tid = threadIdx.x;
    const int key = tid >> 2, c16 = (tid & 3) << 4;
    const unsigned short* kp = qkv16 + ((size_t)(b * 1024 + kc * 64 + key)) * 3072 + 1024 + h * 64 + c16;
    alignas(16) unsigned short kbuf[16];
    const float KSCALE = 8.0f * 1.44269504088896f;   // 8 * log2(e)
    #pragma unroll
    for (int j = 0; j < 16; j += 8) {
        short8 k8 = *reinterpret_cast<const short8*>(kp + j);
        short8 v8 = *reinterpret_cast<const short8*>(kp + 1024 + j);
        #pragma unroll
        for (int c = 0; c < 8; ++c) {
            kbuf[j + c] = f2h(KSCALE * h2f((unsigned short)k8[c]));
            VtT[c16 + j + c][key] = (unsigned short)v8[c];
        }
    }
    const size_t kb = ((size_t)bh * 1024 + kc * 64 + key) * 64 + c16;
    *reinterpret_cast<short8*>(K_g + kb)     = *reinterpret_cast<short8*>(&kbuf[0]);
    *reinterpret_cast<short8*>(K_g + kb + 8) = *reinterpret_cast<short8*>(&kbuf[8]);
    __syncthreads();
    const int d = tid >> 2;
    const size_t vb = ((size_t)bh * 64 + d) * 1024 + (size_t)kc * 64 + c16;
    *reinterpret_cast<short8*>(Vt_g + vb)     = *reinterpret_cast<const short8*>(&VtT[d][c16]);
    *reinterpret_cast<short8*>(Vt_g + vb + 8) = *reinterpret_cast<const short8*>(&VtT[d][c16 + 8]);
}

// ---------------- Flash attention: barrier-free, K/V fragments direct from global ---
// grid: x = bh (64), y = qt (16) -> qt-sharers of a head on ONE XCD (bh%8); per-kt
// K/V tile = 16KB, shared via L1 (4 waves) + L2 (16 qt blocks). No __syncthreads:
// waves free-run (latency hidden by 4 waves/SIMD + MLP). Plds is same-wave RAW only.
// T5 setprio around MFMA clusters (m191: +4-7% in the independent-wave regime).
__global__ __launch_bounds__(256, 4)
void attn_kernel(const unsigned short* __restrict__ qkv16,
                 const unsigned short* __restrict__ K_g,
                 const unsigned short* __restrict__ Vt_g,
                 unsigned short* __restrict__ ctx) {
    __shared__ unsigned short Plds[4][16][72];
    const int bh = blockIdx.x;          // head-major: co-XCD K/V sharing
    const int qt = blockIdx.y;
    const int b = bh >> 4, h = bh & 15;
    const int tid = threadIdx.x;
    const int wave = tid >> 6, lane = tid & 63;
    const int fr = lane & 15, g8 = (lane >> 4) << 3, fq = (lane >> 4) << 2;

    const int qrow = qt * 64 + wave * 16 + fr;
    const unsigned short* qp = qkv16 + ((size_t)(b * 1024 + qrow)) * 3072 + h * 64;
    half8 qf[2];
    qf[0] = *reinterpret_cast<const half8*>(qp + g8);
    qf[1] = *reinterpret_cast<const half8*>(qp + 32 + g8);

    half8 ones;
    #pragma unroll
    for (int j = 0; j < 8; ++j) ones[j] = (_Float16)1.0f;

    float mrun[4];
    f32x4 cacc[4], csum;
    #pragma unroll
    for (int r = 0; r < 4; ++r) { mrun[r] = -3.0e38f; csum[r] = 0.0f; }
    #pragma unroll
    for (int nd = 0; nd < 4; ++nd)
        #pragma unroll
        for (int r = 0; r < 4; ++r) cacc[nd][r] = 0.0f;

    // per-lane fragment base pointers (16B-aligned contiguous reads):
    //   kh[s][n] = K_g[(bh*1024 + kt*64 + n*16+fr)*64 + s*32 + g8]
    //   vv[s][nd] = Vt_g[(bh*64 + nd*16+fr)*1024 + kt*64 + s*32 + g8]
    const unsigned short* Kfb = K_g + ((size_t)bh * 1024 + fr) * 64 + g8;
    const unsigned short* Vfb = Vt_g + ((size_t)bh * 64 + fr) * 1024 + g8;

    for (int kt = 0; kt < 16; ++kt) {
        // K fragments straight from global (tile L1/L2-resident)
        const unsigned short* Kt = Kfb + (size_t)kt * 4096;
        half8 kh[2][4];
        #pragma unroll
        for (int n = 0; n < 4; ++n) {
            kh[0][n] = *reinterpret_cast<const half8*>(Kt + n * 1024);
            kh[1][n] = *reinterpret_cast<const half8*>(Kt + n * 1024 + 32);
        }

        f32x4 S[4];
        #pragma unroll
        for (int n = 0; n < 4; ++n)
            #pragma unroll
            for (int r = 0; r < 4; ++r) S[n][r] = 0.0f;
        __builtin_amdgcn_s_setprio(1);
        #pragma unroll
        for (int s_ = 0; s_ < 2; ++s_)
            #pragma unroll
            for (int n = 0; n < 4; ++n)
                S[n] = __builtin_amdgcn_mfma_f32_16x16x32_f16(qf[s_], kh[s_][n], S[n], 0, 0, 0);
        __builtin_amdgcn_s_setprio(0);

        // V fragments: issue now, land during softmax VALU below
        const unsigned short* Vt = Vfb + kt * 64;
        half8 vv[2][4];
        #pragma unroll
        for (int nd = 0; nd < 4; ++nd) {
            vv[0][nd] = *reinterpret_cast<const half8*>(Vt + (size_t)nd * 16384);
            vv[1][nd] = *reinterpret_cast<const half8*>(Vt + (size_t)nd * 16384 + 32);
        }

        // row max over 16 lanes (4 shuffle rounds)
        float mt[4];
        #pragma unroll
        for (int r = 0; r < 4; ++r)
            mt[r] = fmaxf(fmaxf(S[0][r], S[1][r]), fmaxf(S[2][r], S[3][r]));
        #pragma unroll
        for (int r = 0; r < 4; ++r) {
            mt[r] = fmaxf(mt[r], __shfl_xor(mt[r], 1));
            mt[r] = fmaxf(mt[r], __shfl_xor(mt[r], 2));
            mt[r] = fmaxf(mt[r], __shfl_xor(mt[r], 4));
            mt[r] = fmaxf(mt[r], __shfl_xor(mt[r], 8));
        }
        // defer-max: rescale only when any row max grew > 8 (wave-uniform)
        int grow = 0;
        #pragma unroll
        for (int r = 0; r < 4; ++r) grow |= (mt[r] > mrun[r] + 8.0f) ? 1 : 0;
        if (__any(grow)) {
            #pragma unroll
            for (int r = 0; r < 4; ++r) {
                float mnew = fmaxf(mrun[r], mt[r]);
                float sf = __builtin_amdgcn_exp2f(mrun[r] - mnew);
                mrun[r] = mnew;
                csum[r] *= sf;
                #pragma unroll
                for (int nd = 0; nd < 4; ++nd) cacc[nd][r] *= sf;
            }
        }
        // P = exp2(S - m), bounded by 2^8; per-wave LDS slab (same-wave RAW)
        #pragma unroll
        for (int r = 0; r < 4; ++r)
            #pragma unroll
            for (int n = 0; n < 4; ++n)
                Plds[wave][fq + r][n * 16 + fr] =
                    f2h(__builtin_amdgcn_exp2f(S[n][r] - mrun[r]));
        __builtin_amdgcn_s_setprio(1);
        #pragma unroll
        for (int s_ = 0; s_ < 2; ++s_) {
            half8 pa = *reinterpret_cast<const half8*>(&Plds[wave][fr][s_ * 32 + g8]);
            #pragma unroll
            for (int nd = 0; nd < 4; ++nd)
                cacc[nd] = __builtin_amdgcn_mfma_f32_16x16x32_f16(pa, vv[s_][nd], cacc[nd], 0, 0, 0);
            csum = __builtin_amdgcn_mfma_f32_16x16x32_f16(pa, ones, csum, 0, 0, 0);
        }
        __builtin_amdgcn_s_setprio(0);
    }
    #pragma unroll
    for (int r = 0; r < 4; ++r) {
        const float inv = 1.0f / csum[r];
        const int row = qt * 64 + wave * 16 + fq + r;
        unsigned short* cp = ctx + ((size_t)(b * 1024 + row)) * 1024 + h * 64;
        #pragma unroll
        for (int nd = 0; nd < 4; ++nd)
            cp[nd * 16 + fr] = f2h(cacc[nd][r] * inv);
    }
}

// ---------------- launch ----------------
extern "C" void kernel_launch(void* const* d_in, const int* in_sizes, int n_in,
                              void* d_out, int out_size, void* d_ws, size_t ws_size,
                              hipStream_t stream) {
    const float* x      = (const float*)d_in[0];
    const float* norm_g = (const float*)d_in[1];
    const float* norm_b = (const float*)d_in[2];
    const float* w_qkv  = (const float*)d_in[3];
    const float* b_qkv  = (const float*)d_in[4];
    const float* w_proj = (const float*)d_in[5];
    const float* b_proj = (const float*)d_in[6];
    const float* w_fc1  = (const float*)d_in[7];
    const float* b_fc1  = (const float*)d_in[8];
    const float* w_fc2  = (const float*)d_in[9];
    const float* b_fc2  = (const float*)d_in[10];
    float* out = (float*)d_out;
    char* ws = (char*)d_ws;

    size_t off = 0;
    unsigned short* wqkvT  = (unsigned short*)(ws + off); off += (size_t)3072 * 1024 * 2;
    unsigned short* wprojT = (unsigned short*)(ws + off); off += (size_t)1024 * 1024 * 2;
    unsigned short* wfc1T  = (unsigned short*)(ws + off); off += (size_t)4096 * 1024 * 2;
    unsigned short* wfc2T  = (unsigned short*)(ws + off); off += (size_t)1024 * 4096 * 2;
    unsigned short* ctxb   = (unsigned short*)(ws + off); off += (size_t)4096 * 1024 * 2;
    char* G = ws + off;
    // G region timeline (byte offsets; watermark identical to round 16):
    //   h1     ( 8.4 MB) at G+0         : ln -> qkv GEMM
    //   qkv16  (25.2 MB) at G+8388608   : qkv GEMM -> attn (q) / kv_conv
    //   K_g    ( 8.4 MB) at G+0         : kv_conv -> attn (overlaps dead h1)
    //   Vt_g   ( 8.4 MB) at G+33554432  : kv_conv -> attn
    //   fc1o   (33.5 MB) at G+0         : fc1 -> fc2
    //   h2     ( 8.4 MB) at G+41943040  : ln2 -> fc1 (dead before fc2)
    //   fc2ph  [4][4096][1024] fp16 (33.5 MB) at G+33554432 : fc2 partials -> red
    //   x1h    ( 8.4 MB) at G+67108864  : proj -> ln2/red (fp16 residual)
    unsigned short* h1    = (unsigned short*)G;
    unsigned short* qkv16 = (unsigned short*)(G + (size_t)8388608);
    unsigned short* K_g   = (unsigned short*)G;
    unsigned short* Vt_g  = (unsigned short*)(G + (size_t)33554432);
    unsigned short* fc1o  = (unsigned short*)G;
    unsigned short* h2    = (unsigned short*)(G + (size_t)41943040);
    unsigned short* fc2ph = (unsigned short*)(G + (size_t)33554432);
    unsigned short* x1h   = (unsigned short*)(G + (size_t)67108864);

    // weight prep (fused single launch)
    transpose_all<<<12288, 256, 0, stream>>>(w_qkv, w_proj, w_fc1, w_fc2,
                                             wqkvT, wprojT, wfc1T, wfc2T);

    // h1 = LN(x) fp16 ; qkv16 = fp16(h1 @ w_qkv + b)   (gemm_mid: 384 blocks)
    ln_kernel<0><<<4096, 256, 0, stream>>>(x, norm_g, norm_b, h1);
    gemm_mid<0, 1><<<384, 512, 0, stream>>>(h1, wqkvT, b_qkv, qkv16,
                                            4096, 3072, 1024, 1024, 1024, 3072);

    // compact K (x 8*log2e) and V^T
    kv_conv<<<dim3(16, 64), 256, 0, stream>>>(qkv16, K_g, Vt_g);

    // attention -> ctx (fp16); barrier-free, head-major grid for XCD-local K/V
    attn_kernel<<<dim3(64, 16), 256, 0, stream>>>(qkv16, K_g, Vt_g, ctxb);

    // x1h = fp16(x + ctx @ w_proj + b)   (2-phase BM=64 + XCD remap)
    gemm_bt<5, 64, 1><<<512, 256, 0, stream>>>(ctxb, wprojT, b_proj, x, x1h,
                                               4096, 1024, 1024, 1024, 1024, 1024);

    // h2 = LN(x1h) ; fc1 = gelu(h2 @ w_fc1 + b)   (gemm_mid: 512 blocks = 2/CU)
    ln_kernel<1><<<4096, 256, 0, stream>>>(x1h, norm_g, norm_b, h2);
    gemm_mid<2, 1><<<512, 512, 0, stream>>>(h2, wfc1T, b_fc1, fc1o,
                                            4096, 4096, 1024, 1024, 1024, 4096);

    // fc2: gemm_mid split-K=4 (512 blocks = 2/CU), XCD-local A-tiles, fp16 partials
    gemm_mid<4, 4><<<512, 512, 0, stream>>>(fc1o, wfc2T, nullptr, fc2ph,
                                            4096, 1024, 1024, 4096, 4096, 1024);
    // out(f32) = x1h + b_fc2 + sum partials
    red_h<4><<<4096, 256, 0, stream>>>(fc2ph, x1h, b_fc2, out);
}

// Round 18
// 244.919 us; speedup vs baseline: 1.2701x; 1.2701x over previous
//
#include <hip/hip_runtime.h>
#include <hip/hip_bf16.h>

typedef __attribute__((ext_vector_type(8))) short short8;
typedef __attribute__((ext_vector_type(8))) _Float16 half8;
typedef __attribute__((ext_vector_type(4))) float f32x4;

__device__ __forceinline__ unsigned short f2h(float f) {
    _Float16 h = (_Float16)f;
    return *reinterpret_cast<unsigned short*>(&h);
}
__device__ __forceinline__ float h2f(unsigned short u) {
    _Float16 h = *reinterpret_cast<_Float16*>(&u);
    return (float)h;
}

// async global->LDS, 16B per lane, wave-uniform LDS base + lane*16 dest
__device__ __forceinline__ void gld_lds16(const unsigned short* g, unsigned short* l) {
    __builtin_amdgcn_global_load_lds(
        (const __attribute__((address_space(1))) unsigned int*)g,
        (__attribute__((address_space(3))) unsigned int*)l, 16, 0, 0);
}

// ---------------- fused weight transpose + fp16 convert (one launch) ----------------
__global__ __launch_bounds__(256)
void transpose_all(const float* __restrict__ W0, const float* __restrict__ W1,
                   const float* __restrict__ W2, const float* __restrict__ W3,
                   unsigned short* __restrict__ o0, unsigned short* __restrict__ o1,
                   unsigned short* __restrict__ o2, unsigned short* __restrict__ o3) {
    __shared__ float tile[32][33];
    const int bid = blockIdx.x;
    const float* W; unsigned short* out; int K, N, loc;
    if (bid < 3072)      { W = W0; out = o0; K = 1024; N = 3072; loc = bid; }
    else if (bid < 4096) { W = W1; out = o1; K = 1024; N = 1024; loc = bid - 3072; }
    else if (bid < 8192) { W = W2; out = o2; K = 1024; N = 4096; loc = bid - 4096; }
    else                 { W = W3; out = o3; K = 4096; N = 1024; loc = bid - 8192; }
    const int nx = N >> 5;
    const int n0 = (loc % nx) << 5, k0 = (loc / nx) << 5;
    const int tid = threadIdx.x;
    const int r = tid >> 3, c4 = (tid & 7) << 2;
    float4 v = *reinterpret_cast<const float4*>(W + (size_t)(k0 + r) * N + n0 + c4);
    tile[r][c4 + 0] = v.x; tile[r][c4 + 1] = v.y;
    tile[r][c4 + 2] = v.z; tile[r][c4 + 3] = v.w;
    __syncthreads();
    const int n = n0 + r;
    ushort4 o;
    o.x = f2h(tile[c4 + 0][r]); o.y = f2h(tile[c4 + 1][r]);
    o.z = f2h(tile[c4 + 2][r]); o.w = f2h(tile[c4 + 3][r]);
    *reinterpret_cast<ushort4*>(out + (size_t)n * K + k0 + c4) = o;
}

// ---------------- LayerNorm -> fp16 [row][1024]; input f32 (IN16=0) or fp16 (IN16=1)
template<int IN16>
__global__ __launch_bounds__(256)
void ln_kernel(const void* __restrict__ xin, const float* __restrict__ gw,
               const float* __restrict__ bw, unsigned short* __restrict__ out) {
    const int row = blockIdx.x, tid = threadIdx.x;
    float v0, v1, v2, v3;
    if (IN16) {
        const unsigned short* xr = (const unsigned short*)xin + (size_t)row * 1024;
        ushort4 u = *reinterpret_cast<const ushort4*>(xr + tid * 4);
        v0 = h2f(u.x); v1 = h2f(u.y); v2 = h2f(u.z); v3 = h2f(u.w);
    } else {
        const float* xr = (const float*)xin + (size_t)row * 1024;
        float4 v = *reinterpret_cast<const float4*>(xr + tid * 4);
        v0 = v.x; v1 = v.y; v2 = v.z; v3 = v.w;
    }
    float s = v0 + v1 + v2 + v3;
    float sq = v0 * v0 + v1 * v1 + v2 * v2 + v3 * v3;
    #pragma unroll
    for (int off = 1; off < 64; off <<= 1) {
        s  += __shfl_xor(s, off);
        sq += __shfl_xor(sq, off);
    }
    __shared__ float ps[4], pq[4];
    const int wave = tid >> 6;
    if ((tid & 63) == 0) { ps[wave] = s; pq[wave] = sq; }
    __syncthreads();
    s  = ps[0] + ps[1] + ps[2] + ps[3];
    sq = pq[0] + pq[1] + pq[2] + pq[3];
    const float mu = s * (1.0f / 1024.0f);
    const float var = sq * (1.0f / 1024.0f) - mu * mu;
    const float rs = rsqrtf(var + 1e-5f);
    float4 gv = *reinterpret_cast<const float4*>(gw + tid * 4);
    float4 bv = *reinterpret_cast<const float4*>(bw + tid * 4);
    ushort4 o;
    o.x = f2h((v0 - mu) * rs * gv.x + bv.x);
    o.y = f2h((v1 - mu) * rs * gv.y + bv.y);
    o.z = f2h((v2 - mu) * rs * gv.z + bv.z);
    o.w = f2h((v3 - mu) * rs * gv.w + bv.w);
    *reinterpret_cast<ushort4*>(out + (size_t)row * 1024 + tid * 4) = o;
}

// ---------------- mid-tile GEMM: 128x256, BK=32, 8 waves (2Mx4N), 48KB LDS ----------
// 2-phase prefetch; one barrier per K-tile; chunk-swizzled LDS (2-way conflicts, free).
// NZ==1: per-XCD contiguous bm stripes. NZ>1: xcd = bm%8, bn fastest.
// EPI 0: fp16 = acc+bias ; EPI 2: fp16 = gelu(acc+bias) ; EPI 4: fp16 raw partial
template<int EPI, int NZ>
__global__ __launch_bounds__(512, 4)
void gemm_mid(const unsigned short* __restrict__ A, const unsigned short* __restrict__ Bt,
              const float* __restrict__ bias, void* Cout,
              int M, int N, int K, int lda, int ldb, int ldc) {
    __shared__ unsigned short As[2][128 * 32];   // 8KB per buf
    __shared__ unsigned short Bs[2][256 * 32];   // 16KB per buf (total 48KB)
    const int tid = threadIdx.x;
    const int wave = tid >> 6, lane = tid & 63;
    const int nx = N >> 8;
    int bm, bn, z;
    if (NZ == 1) {
        const int nwg = gridDim.x;
        const int swz = (blockIdx.x & 7) * (nwg >> 3) + (blockIdx.x >> 3);
        bm = (swz / nx) << 7; bn = (swz % nx) << 8; z = 0;
    } else {
        int bid = blockIdx.x;
        const int xcd = bid & 7; int rest = bid >> 3;
        bn = (rest % nx) << 8; rest /= nx;
        z = rest % NZ; rest /= NZ;
        bm = (rest * 8 + xcd) << 7;              // requires (M/128) % 8 == 0
    }
    const size_t koff = (size_t)z * K;
    const int wm = wave >> 2, wn = wave & 3;     // 2 M-waves x 4 N-waves, 64x64 each
    const int fr = lane & 15, g8 = (lane >> 4) << 3, fq = (lane >> 4) << 2;
    const int jq = g8 >> 3;          // logical 16B chunk (0..3)
    const int sx2 = (fr >> 1) & 3;   // read-side XOR

    const int srow = lane >> 2;
    const int scol = ((lane & 3) ^ ((lane >> 3) & 3)) << 3;
    const unsigned short* gA  = A + (size_t)(bm + wave * 16 + srow) * lda + scol + koff;
    const unsigned short* gB0 = Bt + (size_t)(bn + wave * 32 + srow) * ldb + scol + koff;
    const unsigned short* gB1 = gB0 + (size_t)16 * ldb;
    const int lbA = wave * 512;      // wave-uniform LDS bases (shorts)
    const int lbB = wave * 1024;

    f32x4 acc[4][4];
    #pragma unroll
    for (int m = 0; m < 4; ++m)
        #pragma unroll
        for (int n_ = 0; n_ < 4; ++n_)
            #pragma unroll
            for (int r_ = 0; r_ < 4; ++r_) acc[m][n_][r_] = 0.0f;

    auto stage = [&](int buf, int k0) {
        gld_lds16(gA + k0, &As[buf][lbA]);
        gld_lds16(gB0 + k0, &Bs[buf][lbB]);
        gld_lds16(gB1 + k0, &Bs[buf][lbB + 512]);
    };
    auto compute = [&](int buf) {
        half8 af[4], bfv[4];
        #pragma unroll
        for (int m = 0; m < 4; ++m)
            af[m] = *reinterpret_cast<const half8*>(
                &As[buf][(wm * 64 + m * 16 + fr) * 32 + ((jq ^ sx2) << 3)]);
        #pragma unroll
        for (int n_ = 0; n_ < 4; ++n_)
            bfv[n_] = *reinterpret_cast<const half8*>(
                &Bs[buf][(wn * 64 + n_ * 16 + fr) * 32 + ((jq ^ sx2) << 3)]);
        #pragma unroll
        for (int m = 0; m < 4; ++m)
            #pragma unroll
            for (int n_ = 0; n_ < 4; ++n_)
                acc[m][n_] = __builtin_amdgcn_mfma_f32_16x16x32_f16(af[m], bfv[n_], acc[m][n_], 0, 0, 0);
    };

    const int nt = K >> 5;   // even for all our shapes
    stage(0, 0);
    __syncthreads();
    int k0 = 32;
    for (int t = 0; t < nt - 2; t += 2) {
        stage(1, k0);
        compute(0);
        __syncthreads();
        stage(0, k0 + 32);
        compute(1);
        __syncthreads();
        k0 += 64;
    }
    stage(1, k0);
    compute(0);
    __syncthreads();
    compute(1);

    if (EPI == 4) {
        unsigned short* P = reinterpret_cast<unsigned short*>(Cout) +
                            (size_t)z * (size_t)M * ldc;
        #pragma unroll
        for (int n_ = 0; n_ < 4; ++n_) {
            const int col = bn + wn * 64 + n_ * 16 + fr;
            #pragma unroll
            for (int m = 0; m < 4; ++m)
                #pragma unroll
                for (int r_ = 0; r_ < 4; ++r_) {
                    const int row = bm + wm * 64 + m * 16 + fq + r_;
                    P[(size_t)row * ldc + col] = f2h(acc[m][n_][r_]);
                }
        }
        return;
    }

    unsigned short* o16 = reinterpret_cast<unsigned short*>(Cout);
    #pragma unroll
    for (int n_ = 0; n_ < 4; ++n_) {
        const int col = bn + wn * 64 + n_ * 16 + fr;
        const float bc = bias[col];
        #pragma unroll
        for (int m = 0; m < 4; ++m) {
            #pragma unroll
            for (int r_ = 0; r_ < 4; ++r_) {
                const int row = bm + wm * 64 + m * 16 + fq + r_;
                const size_t idx = (size_t)row * ldc + col;
                float v = acc[m][n_][r_] + bc;
                if (EPI == 0) {
                    o16[idx] = f2h(v);
                } else {
                    float ge = 0.5f * v * (1.0f + erff(v * 0.70710678118654752f));
                    o16[idx] = f2h(ge);
                }
            }
        }
    }
}

// ---------------- 2-phase GEMM (skinny shapes), BK=32 chunk-swizzle -----------------
// REMAP=1: 1-D grid, xcd = bid&7 == bm%8, bn fastest within XCD.
// EPI 5: fp16 = acc + bias + resid(f32)   (x1h residual-out for proj)
template<int EPI, int BM, int REMAP>
__global__ __launch_bounds__(256)
void gemm_bt(const unsigned short* __restrict__ A, const unsigned short* __restrict__ Bt,
             const float* __restrict__ bias, const float* resid,
             void* Cout, int M, int N, int K, int lda, int ldb, int ldc) {
    constexpr int MF = BM / 32;
    __shared__ unsigned short As[2][BM * 32];
    __shared__ unsigned short Bs[2][128 * 32];
    const int tid = threadIdx.x;
    const int wave = tid >> 6, lane = tid & 63;
    int bm, bn;
    if (REMAP) {
        const int nxr = N >> 7;
        int bid = blockIdx.x;
        const int xcd = bid & 7; int rest = bid >> 3;
        bn = (rest % nxr) << 7; rest /= nxr;
        bm = (rest * 8 + xcd) * BM;              // requires (M/BM) % 8 == 0
    } else {
        bm = blockIdx.y * BM; bn = blockIdx.x << 7;
    }
    const int wr = (wave >> 1) * (BM / 2), wc = (wave & 1) << 6;
    const int fr = lane & 15, g8 = (lane >> 4) << 3, fq = (lane >> 4) << 2;
    const int jq = g8 >> 3, sx2 = (fr >> 1) & 3;

    const int srowA = (BM == 128) ? ((wave << 5) + (lane >> 2)) : ((wave << 4) + (lane >> 2));
    const int srowB = (wave << 5) + (lane >> 2);
    const int scol = (((lane & 3) ^ ((lane >> 3) & 3))) << 3;
    const unsigned short* gA0 = A + (size_t)(bm + srowA) * lda + scol;
    const unsigned short* gA1 = gA0 + (size_t)16 * lda;      // BM==128 only
    const unsigned short* gB0 = Bt + (size_t)(bn + srowB) * ldb + scol;
    const unsigned short* gB1 = gB0 + (size_t)16 * ldb;

    f32x4 acc[MF][4];
    #pragma unroll
    for (int m = 0; m < MF; ++m)
        #pragma unroll
        for (int n = 0; n < 4; ++n)
            #pragma unroll
            for (int r = 0; r < 4; ++r) acc[m][n][r] = 0.0f;

    auto stage = [&](int buf, int k0) {
        unsigned short* lA = &As[buf][(BM == 128) ? (wave << 10) : (wave << 9)];
        unsigned short* lB = &Bs[buf][wave << 10];
        gld_lds16(gA0 + k0, lA);
        if constexpr (BM == 128) gld_lds16(gA1 + k0, lA + 512);
        gld_lds16(gB0 + k0, lB);
        gld_lds16(gB1 + k0, lB + 512);
    };
    auto compute = [&](int buf) {
        half8 af[MF], bfv[4];
        #pragma unroll
        for (int m = 0; m < MF; ++m)
            af[m] = *reinterpret_cast<const half8*>(
                &As[buf][(wr + m * 16 + fr) * 32 + ((jq ^ sx2) << 3)]);
        #pragma unroll
        for (int n = 0; n < 4; ++n)
            bfv[n] = *reinterpret_cast<const half8*>(
                &Bs[buf][(wc + n * 16 + fr) * 32 + ((jq ^ sx2) << 3)]);
        #pragma unroll
        for (int m = 0; m < MF; ++m)
            #pragma unroll
            for (int n = 0; n < 4; ++n)
                acc[m][n] = __builtin_amdgcn_mfma_f32_16x16x32_f16(af[m], bfv[n], acc[m][n], 0, 0, 0);
    };

    const int nt = K >> 5;
    stage(0, 0);
    __syncthreads();
    int k0 = 32;
    for (int t = 0; t < nt - 2; t += 2) {
        stage(1, k0);
        compute(0);
        __syncthreads();
        stage(0, k0 + 32);
        compute(1);
        __syncthreads();
        k0 += 64;
    }
    stage(1, k0);
    compute(0);
    __syncthreads();
    compute(1);

    #pragma unroll
    for (int n = 0; n < 4; ++n) {
        const int col = bn + wc + n * 16 + fr;
        const float bc = bias[col];
        #pragma unroll
        for (int m = 0; m < MF; ++m) {
            #pragma unroll
            for (int r = 0; r < 4; ++r) {
                const int row = bm + wr + m * 16 + fq + r;
                const size_t idx = (size_t)row * ldc + col;
                float v = acc[m][n][r] + bc;
                // EPI 5: fp16 residual-out
                reinterpret_cast<unsigned short*>(Cout)[idx] = f2h(v + resid[idx]);
            }
        }
    }
}

// ---------------- split-K reduce: out(f32) = x1h(fp16) + bias + sum_z p[z](fp16) ----
template<int Z>
__global__ __launch_bounds__(256)
void red_h(const unsigned short* __restrict__ p, const unsigned short* __restrict__ x1h,
           const float* __restrict__ bias, float* out) {
    const size_t MN = (size_t)4096 * 1024;
    const size_t i = ((size_t)blockIdx.x * 256 + threadIdx.x) * 4;
    ushort4 xh = *reinterpret_cast<const ushort4*>(x1h + i);
    float4 bb = *reinterpret_cast<const float4*>(bias + (i & 1023));
    float o0 = h2f(xh.x) + bb.x, o1 = h2f(xh.y) + bb.y;
    float o2 = h2f(xh.z) + bb.z, o3 = h2f(xh.w) + bb.w;
    #pragma unroll
    for (int z = 0; z < Z; ++z) {
        ushort4 a = *reinterpret_cast<const ushort4*>(p + (size_t)z * MN + i);
        o0 += h2f(a.x); o1 += h2f(a.y); o2 += h2f(a.z); o3 += h2f(a.w);
    }
    float4 o; o.x = o0; o.y = o1; o.z = o2; o.w = o3;
    *reinterpret_cast<float4*>(out + i) = o;
}

// ---------------- K/V compaction ----------------
// K scaled by 8*log2(e): P = exp2(S - m) == exp((q.k)*8 - m'), one mul cheaper.
__global__ __launch_bounds__(256)
void kv_conv(const unsigned short* __restrict__ qkv16, unsigned short* __restrict__ K_g,
             unsigned short* __restrict__ Vt_g) {
    __shared__ unsigned short VtT[64][72];
    const int kc = blockIdx.x;
    const int bh = blockIdx.y;
    const int b = bh >> 4, h = bh & 15;
    const int tid = threadIdx.x;
    const int key = tid >> 2, c16 = (tid & 3) << 4;
    const unsigned short* kp = qkv16 + ((size_t)(b * 1024 + kc * 64 + key)) * 3072 + 1024 + h * 64 + c16;
    alignas(16) unsigned short kbuf[16];
    const float KSCALE = 8.0f * 1.44269504088896f;   // 8 * log2(e)
    #pragma unroll
    for (int j = 0; j < 16; j += 8) {
        short8 k8 = *reinterpret_cast<const short8*>(kp + j);
        short8 v8 = *reinterpret_cast<const short8*>(kp + 1024 + j);
        #pragma unroll
        for (int c = 0; c < 8; ++c) {
            kbuf[j + c] = f2h(KSCALE * h2f((unsigned short)k8[c]));
            VtT[c16 + j + c][key] = (unsigned short)v8[c];
        }
    }
    const size_t kb = ((size_t)bh * 1024 + kc * 64 + key) * 64 + c16;
    *reinterpret_cast<short8*>(K_g + kb)     = *reinterpret_cast<short8*>(&kbuf[0]);
    *reinterpret_cast<short8*>(K_g + kb + 8) = *reinterpret_cast<short8*>(&kbuf[8]);
    __syncthreads();
    const int d = tid >> 2;
    const size_t vb = ((size_t)bh * 64 + d) * 1024 + (size_t)kc * 64 + c16;
    *reinterpret_cast<short8*>(Vt_g + vb)     = *reinterpret_cast<const short8*>(&VtT[d][c16]);
    *reinterpret_cast<short8*>(Vt_g + vb + 8) = *reinterpret_cast<const short8*>(&VtT[d][c16 + 8]);
}

// ---------------- Flash attention (fp16, QBLK=64, exp2 + ones-MFMA + defer-max) -----
// grid: x = bh (64), y = qt (16) -> all qt-sharers of a head on ONE XCD (bh%8).
// LDS-staged K/V (latency amortization) + T14 register prefetch of next tile.
__global__ __launch_bounds__(256)
void attn_kernel(const unsigned short* __restrict__ qkv16,
                 const unsigned short* __restrict__ K_g,
                 const unsigned short* __restrict__ Vt_g,
                 unsigned short* __restrict__ ctx) {
    __shared__ unsigned short Kh[64][72];
    __shared__ unsigned short Vt[64][72];
    __shared__ unsigned short Plds[4][16][72];
    const int bh = blockIdx.x;          // head-major: co-XCD K/V sharing
    const int qt = blockIdx.y;
    const int b = bh >> 4, h = bh & 15;
    const int tid = threadIdx.x;
    const int wave = tid >> 6, lane = tid & 63;
    const int fr = lane & 15, g8 = (lane >> 4) << 3, fq = (lane >> 4) << 2;

    const int qrow = qt * 64 + wave * 16 + fr;
    const unsigned short* qp = qkv16 + ((size_t)(b * 1024 + qrow)) * 3072 + h * 64;
    half8 qf[2];
    qf[0] = *reinterpret_cast<const half8*>(qp + g8);
    qf[1] = *reinterpret_cast<const half8*>(qp + 32 + g8);

    half8 ones;
    #pragma unroll
    for (int j = 0; j < 8; ++j) ones[j] = (_Float16)1.0f;

    float mrun[4];
    f32x4 cacc[4], csum;
    #pragma unroll
    for (int r = 0; r < 4; ++r) { mrun[r] = -3.0e38f; csum[r] = 0.0f; }
    #pragma unroll
    for (int nd = 0; nd < 4; ++nd)
        #pragma unroll
        for (int r = 0; r < 4; ++r) cacc[nd][r] = 0.0f;

    const int skey = tid >> 2, sc16 = (tid & 3) << 4;
    const unsigned short* kgp = K_g + ((size_t)bh * 1024 + skey) * 64 + sc16;
    const unsigned short* vgp = Vt_g + ((size_t)bh * 64 + skey) * 1024 + sc16;

    short8 ka = *reinterpret_cast<const short8*>(kgp);
    short8 kb = *reinterpret_cast<const short8*>(kgp + 8);
    short8 va = *reinterpret_cast<const short8*>(vgp);
    short8 vb = *reinterpret_cast<const short8*>(vgp + 8);

    for (int kt = 0; kt < 16; ++kt) {
        __syncthreads();
        *reinterpret_cast<short8*>(&Kh[skey][sc16])     = ka;
        *reinterpret_cast<short8*>(&Kh[skey][sc16 + 8]) = kb;
        *reinterpret_cast<short8*>(&Vt[skey][sc16])     = va;
        *reinterpret_cast<short8*>(&Vt[skey][sc16 + 8]) = vb;
        __syncthreads();
        // T14: issue next tile's loads; hide under compute
        const int ktn = (kt < 15) ? kt + 1 : 15;
        ka = *reinterpret_cast<const short8*>(kgp + (size_t)ktn * 4096);
        kb = *reinterpret_cast<const short8*>(kgp + (size_t)ktn * 4096 + 8);
        va = *reinterpret_cast<const short8*>(vgp + ktn * 64);
        vb = *reinterpret_cast<const short8*>(vgp + ktn * 64 + 8);

        f32x4 S[4];
        #pragma unroll
        for (int n = 0; n < 4; ++n)
            #pragma unroll
            for (int r = 0; r < 4; ++r) S[n][r] = 0.0f;
        #pragma unroll
        for (int s_ = 0; s_ < 2; ++s_)
            #pragma unroll
            for (int n = 0; n < 4; ++n) {
                half8 kh = *reinterpret_cast<const half8*>(&Kh[n * 16 + fr][s_ * 32 + g8]);
                S[n] = __builtin_amdgcn_mfma_f32_16x16x32_f16(qf[s_], kh, S[n], 0, 0, 0);
            }

        // row max over 16 lanes (4 shuffle rounds)
        float mt[4];
        #pragma unroll
        for (int r = 0; r < 4; ++r)
            mt[r] = fmaxf(fmaxf(S[0][r], S[1][r]), fmaxf(S[2][r], S[3][r]));
        #pragma unroll
        for (int r = 0; r < 4; ++r) {
            mt[r] = fmaxf(mt[r], __shfl_xor(mt[r], 1));
            mt[r] = fmaxf(mt[r], __shfl_xor(mt[r], 2));
            mt[r] = fmaxf(mt[r], __shfl_xor(mt[r], 4));
            mt[r] = fmaxf(mt[r], __shfl_xor(mt[r], 8));
        }
        // defer-max: rescale only when any row max grew > 8 (wave-uniform)
        int grow = 0;
        #pragma unroll
        for (int r = 0; r < 4; ++r) grow |= (mt[r] > mrun[r] + 8.0f) ? 1 : 0;
        if (__any(grow)) {
            #pragma unroll
            for (int r = 0; r < 4; ++r) {
                float mnew = fmaxf(mrun[r], mt[r]);
                float sf = __builtin_amdgcn_exp2f(mrun[r] - mnew);
                mrun[r] = mnew;
                csum[r] *= sf;
                #pragma unroll
                for (int nd = 0; nd < 4; ++nd) cacc[nd][r] *= sf;
            }
        }
        // P = exp2(S - m), bounded by 2^8; per-wave LDS slab (same-wave RAW)
        #pragma unroll
        for (int r = 0; r < 4; ++r)
            #pragma unroll
            for (int n = 0; n < 4; ++n)
                Plds[wave][fq + r][n * 16 + fr] =
                    f2h(__builtin_amdgcn_exp2f(S[n][r] - mrun[r]));
        #pragma unroll
        for (int s_ = 0; s_ < 2; ++s_) {
            half8 pa = *reinterpret_cast<const half8*>(&Plds[wave][fr][s_ * 32 + g8]);
            #pragma unroll
            for (int nd = 0; nd < 4; ++nd) {
                half8 vb8 = *reinterpret_cast<const half8*>(&Vt[nd * 16 + fr][s_ * 32 + g8]);
                cacc[nd] = __builtin_amdgcn_mfma_f32_16x16x32_f16(pa, vb8, cacc[nd], 0, 0, 0);
            }
            csum = __builtin_amdgcn_mfma_f32_16x16x32_f16(pa, ones, csum, 0, 0, 0);
        }
    }
    #pragma unroll
    for (int r = 0; r < 4; ++r) {
        const float inv = 1.0f / csum[r];
        const int row = qt * 64 + wave * 16 + fq + r;
        unsigned short* cp = ctx + ((size_t)(b * 1024 + row)) * 1024 + h * 64;
        #pragma unroll
        for (int nd = 0; nd < 4; ++nd)
            cp[nd * 16 + fr] = f2h(cacc[nd][r] * inv);
    }
}

// ---------------- launch ----------------
extern "C" void kernel_launch(void* const* d_in, const int* in_sizes, int n_in,
                              void* d_out, int out_size, void* d_ws, size_t ws_size,
                              hipStream_t stream) {
    const float* x      = (const float*)d_in[0];
    const float* norm_g = (const float*)d_in[1];
    const float* norm_b = (const float*)d_in[2];
    const float* w_qkv  = (const float*)d_in[3];
    const float* b_qkv  = (const float*)d_in[4];
    const float* w_proj = (const float*)d_in[5];
    const float* b_proj = (const float*)d_in[6];
    const float* w_fc1  = (const float*)d_in[7];
    const float* b_fc1  = (const float*)d_in[8];
    const float* w_fc2  = (const float*)d_in[9];
    const float* b_fc2  = (const float*)d_in[10];
    float* out = (float*)d_out;
    char* ws = (char*)d_ws;

    size_t off = 0;
    unsigned short* wqkvT  = (unsigned short*)(ws + off); off += (size_t)3072 * 1024 * 2;
    unsigned short* wprojT = (unsigned short*)(ws + off); off += (size_t)1024 * 1024 * 2;
    unsigned short* wfc1T  = (unsigned short*)(ws + off); off += (size_t)4096 * 1024 * 2;
    unsigned short* wfc2T  = (unsigned short*)(ws + off); off += (size_t)1024 * 4096 * 2;
    unsigned short* ctxb   = (unsigned short*)(ws + off); off += (size_t)4096 * 1024 * 2;
    char* G = ws + off;
    // G region timeline (byte offsets; watermark identical to round 16):
    //   h1     ( 8.4 MB) at G+0         : ln -> qkv GEMM
    //   qkv16  (25.2 MB) at G+8388608   : qkv GEMM -> attn (q) / kv_conv
    //   K_g    ( 8.4 MB) at G+0         : kv_conv -> attn (overlaps dead h1)
    //   Vt_g   ( 8.4 MB) at G+33554432  : kv_conv -> attn
    //   fc1o   (33.5 MB) at G+0         : fc1 -> fc2
    //   h2     ( 8.4 MB) at G+41943040  : ln2 -> fc1 (dead before fc2)
    //   fc2ph  [4][4096][1024] fp16 (33.5 MB) at G+33554432 : fc2 partials -> red
    //   x1h    ( 8.4 MB) at G+67108864  : proj -> ln2/red (fp16 residual)
    unsigned short* h1    = (unsigned short*)G;
    unsigned short* qkv16 = (unsigned short*)(G + (size_t)8388608);
    unsigned short* K_g   = (unsigned short*)G;
    unsigned short* Vt_g  = (unsigned short*)(G + (size_t)33554432);
    unsigned short* fc1o  = (unsigned short*)G;
    unsigned short* h2    = (unsigned short*)(G + (size_t)41943040);
    unsigned short* fc2ph = (unsigned short*)(G + (size_t)33554432);
    unsigned short* x1h   = (unsigned short*)(G + (size_t)67108864);

    // weight prep (fused single launch)
    transpose_all<<<12288, 256, 0, stream>>>(w_qkv, w_proj, w_fc1, w_fc2,
                                             wqkvT, wprojT, wfc1T, wfc2T);

    // h1 = LN(x) fp16 ; qkv16 = fp16(h1 @ w_qkv + b)   (gemm_mid: 384 blocks)
    ln_kernel<0><<<4096, 256, 0, stream>>>(x, norm_g, norm_b, h1);
    gemm_mid<0, 1><<<384, 512, 0, stream>>>(h1, wqkvT, b_qkv, qkv16,
                                            4096, 3072, 1024, 1024, 1024, 3072);

    // compact K (x 8*log2e) and V^T
    kv_conv<<<dim3(16, 64), 256, 0, stream>>>(qkv16, K_g, Vt_g);

    // attention -> ctx (fp16); head-major grid for XCD-local K/V
    attn_kernel<<<dim3(64, 16), 256, 0, stream>>>(qkv16, K_g, Vt_g, ctxb);

    // x1h = fp16(x + ctx @ w_proj + b)   (2-phase BM=64 + XCD remap)
    gemm_bt<5, 64, 1><<<512, 256, 0, stream>>>(ctxb, wprojT, b_proj, x, x1h,
                                               4096, 1024, 1024, 1024, 1024, 1024);

    // h2 = LN(x1h) ; fc1 = gelu(h2 @ w_fc1 + b)   (gemm_mid: 512 blocks = 2/CU)
    ln_kernel<1><<<4096, 256, 0, stream>>>(x1h, norm_g, norm_b, h2);
    gemm_mid<2, 1><<<512, 512, 0, stream>>>(h2, wfc1T, b_fc1, fc1o,
                                            4096, 4096, 1024, 1024, 1024, 4096);

    // fc2: gemm_mid split-K=4 (512 blocks = 2/CU), XCD-local A-tiles, fp16 partials
    gemm_mid<4, 4><<<512, 512, 0, stream>>>(fc1o, wfc2T, nullptr, fc2ph,
                                            4096, 1024, 1024, 4096, 4096, 1024);
    // out(f32) = x1h + b_fc2 + sum partials
    red_h<4><<<4096, 256, 0, stream>>>(fc2ph, x1h, b_fc2, out);
}

// Round 19
// 235.444 us; speedup vs baseline: 1.3212x; 1.0402x over previous
//
#include <hip/hip_runtime.h>
#include <hip/hip_bf16.h>

typedef __attribute__((ext_vector_type(8))) short short8;
typedef __attribute__((ext_vector_type(8))) _Float16 half8;
typedef __attribute__((ext_vector_type(4))) float f32x4;

__device__ __forceinline__ unsigned short f2h(float f) {
    _Float16 h = (_Float16)f;
    return *reinterpret_cast<unsigned short*>(&h);
}
__device__ __forceinline__ float h2f(unsigned short u) {
    _Float16 h = *reinterpret_cast<_Float16*>(&u);
    return (float)h;
}

// tanh-form GELU: x*sigmoid(1.5957691*(x+0.044715x^3)); max |err vs erf-gelu| ~3e-4
// (below fp16 output quantum). exp2-based: ~8 VALU ops vs ~25-30 for ocml erff.
__device__ __forceinline__ float gelu_fast(float v) {
    float x2 = v * v;
    float t  = v * fmaf(x2, 0.10294322f, 2.3022077f);   // 2z * log2(e)
    float e  = __builtin_amdgcn_exp2f(t);
    return v - v * __builtin_amdgcn_rcpf(e + 1.0f);
}

// async global->LDS, 16B per lane, wave-uniform LDS base + lane*16 dest
__device__ __forceinline__ void gld_lds16(const unsigned short* g, unsigned short* l) {
    __builtin_amdgcn_global_load_lds(
        (const __attribute__((address_space(1))) unsigned int*)g,
        (__attribute__((address_space(3))) unsigned int*)l, 16, 0, 0);
}

// ---------------- fused prep: 4x weight transpose->fp16 + LN(x)->h1 (one launch) ----
// blocks 0..12287: transpose tiles; blocks 12288..16383: LayerNorm rows (f32 input).
__global__ __launch_bounds__(256)
void prep_fused(const float* __restrict__ W0, const float* __restrict__ W1,
                const float* __restrict__ W2, const float* __restrict__ W3,
                unsigned short* __restrict__ o0, unsigned short* __restrict__ o1,
                unsigned short* __restrict__ o2, unsigned short* __restrict__ o3,
                const float* __restrict__ x, const float* __restrict__ gw,
                const float* __restrict__ bw, unsigned short* __restrict__ h1) {
    __shared__ float tile[32][33];
    __shared__ float ps[4], pq[4];
    const int bid = blockIdx.x;
    const int tid = threadIdx.x;
    if (bid < 12288) {
        const float* W; unsigned short* out; int K, N, loc;
        if (bid < 3072)      { W = W0; out = o0; K = 1024; N = 3072; loc = bid; }
        else if (bid < 4096) { W = W1; out = o1; K = 1024; N = 1024; loc = bid - 3072; }
        else if (bid < 8192) { W = W2; out = o2; K = 1024; N = 4096; loc = bid - 4096; }
        else                 { W = W3; out = o3; K = 4096; N = 1024; loc = bid - 8192; }
        const int nx = N >> 5;
        const int n0 = (loc % nx) << 5, k0 = (loc / nx) << 5;
        const int r = tid >> 3, c4 = (tid & 7) << 2;
        float4 v = *reinterpret_cast<const float4*>(W + (size_t)(k0 + r) * N + n0 + c4);
        tile[r][c4 + 0] = v.x; tile[r][c4 + 1] = v.y;
        tile[r][c4 + 2] = v.z; tile[r][c4 + 3] = v.w;
        __syncthreads();
        const int n = n0 + r;
        ushort4 o;
        o.x = f2h(tile[c4 + 0][r]); o.y = f2h(tile[c4 + 1][r]);
        o.z = f2h(tile[c4 + 2][r]); o.w = f2h(tile[c4 + 3][r]);
        *reinterpret_cast<ushort4*>(out + (size_t)n * K + k0 + c4) = o;
        return;
    }
    // LayerNorm branch
    const int row = bid - 12288;
    const float* xr = x + (size_t)row * 1024;
    float4 v = *reinterpret_cast<const float4*>(xr + tid * 4);
    float s = v.x + v.y + v.z + v.w;
    float sq = v.x * v.x + v.y * v.y + v.z * v.z + v.w * v.w;
    #pragma unroll
    for (int off = 1; off < 64; off <<= 1) {
        s  += __shfl_xor(s, off);
        sq += __shfl_xor(sq, off);
    }
    const int wave = tid >> 6;
    if ((tid & 63) == 0) { ps[wave] = s; pq[wave] = sq; }
    __syncthreads();
    s  = ps[0] + ps[1] + ps[2] + ps[3];
    sq = pq[0] + pq[1] + pq[2] + pq[3];
    const float mu = s * (1.0f / 1024.0f);
    const float var = sq * (1.0f / 1024.0f) - mu * mu;
    const float rs = rsqrtf(var + 1e-5f);
    float4 gv = *reinterpret_cast<const float4*>(gw + tid * 4);
    float4 bv = *reinterpret_cast<const float4*>(bw + tid * 4);
    ushort4 o;
    o.x = f2h((v.x - mu) * rs * gv.x + bv.x);
    o.y = f2h((v.y - mu) * rs * gv.y + bv.y);
    o.z = f2h((v.z - mu) * rs * gv.z + bv.z);
    o.w = f2h((v.w - mu) * rs * gv.w + bv.w);
    *reinterpret_cast<ushort4*>(h1 + (size_t)row * 1024 + tid * 4) = o;
}

// ---------------- LayerNorm -> fp16 [row][1024]; fp16 input ----------------
__global__ __launch_bounds__(256)
void ln16_kernel(const unsigned short* __restrict__ xin, const float* __restrict__ gw,
                 const float* __restrict__ bw, unsigned short* __restrict__ out) {
    const int row = blockIdx.x, tid = threadIdx.x;
    const unsigned short* xr = xin + (size_t)row * 1024;
    ushort4 u = *reinterpret_cast<const ushort4*>(xr + tid * 4);
    float v0 = h2f(u.x), v1 = h2f(u.y), v2 = h2f(u.z), v3 = h2f(u.w);
    float s = v0 + v1 + v2 + v3;
    float sq = v0 * v0 + v1 * v1 + v2 * v2 + v3 * v3;
    #pragma unroll
    for (int off = 1; off < 64; off <<= 1) {
        s  += __shfl_xor(s, off);
        sq += __shfl_xor(sq, off);
    }
    __shared__ float ps[4], pq[4];
    const int wave = tid >> 6;
    if ((tid & 63) == 0) { ps[wave] = s; pq[wave] = sq; }
    __syncthreads();
    s  = ps[0] + ps[1] + ps[2] + ps[3];
    sq = pq[0] + pq[1] + pq[2] + pq[3];
    const float mu = s * (1.0f / 1024.0f);
    const float var = sq * (1.0f / 1024.0f) - mu * mu;
    const float rs = rsqrtf(var + 1e-5f);
    float4 gv = *reinterpret_cast<const float4*>(gw + tid * 4);
    float4 bv = *reinterpret_cast<const float4*>(bw + tid * 4);
    ushort4 o;
    o.x = f2h((v0 - mu) * rs * gv.x + bv.x);
    o.y = f2h((v1 - mu) * rs * gv.y + bv.y);
    o.z = f2h((v2 - mu) * rs * gv.z + bv.z);
    o.w = f2h((v3 - mu) * rs * gv.w + bv.w);
    *reinterpret_cast<ushort4*>(out + (size_t)row * 1024 + tid * 4) = o;
}

// ---------------- mid-tile GEMM: 128x256, BK=32, 8 waves (2Mx4N), 48KB LDS ----------
// 2-phase prefetch; one barrier per K-tile; chunk-swizzled LDS (2-way conflicts, free).
// NZ==1: per-XCD contiguous bm stripes. NZ>1: xcd = bm%8, bn fastest.
// EPI 0: fp16 = acc+bias ; EPI 2: fp16 = gelu_fast(acc+bias) ; EPI 4: fp16 raw partial
template<int EPI, int NZ>
__global__ __launch_bounds__(512, 4)
void gemm_mid(const unsigned short* __restrict__ A, const unsigned short* __restrict__ Bt,
              const float* __restrict__ bias, void* Cout,
              int M, int N, int K, int lda, int ldb, int ldc) {
    __shared__ unsigned short As[2][128 * 32];   // 8KB per buf
    __shared__ unsigned short Bs[2][256 * 32];   // 16KB per buf (total 48KB)
    const int tid = threadIdx.x;
    const int wave = tid >> 6, lane = tid & 63;
    const int nx = N >> 8;
    int bm, bn, z;
    if (NZ == 1) {
        const int nwg = gridDim.x;
        const int swz = (blockIdx.x & 7) * (nwg >> 3) + (blockIdx.x >> 3);
        bm = (swz / nx) << 7; bn = (swz % nx) << 8; z = 0;
    } else {
        int bid = blockIdx.x;
        const int xcd = bid & 7; int rest = bid >> 3;
        bn = (rest % nx) << 8; rest /= nx;
        z = rest % NZ; rest /= NZ;
        bm = (rest * 8 + xcd) << 7;              // requires (M/128) % 8 == 0
    }
    const size_t koff = (size_t)z * K;
    const int wm = wave >> 2, wn = wave & 3;     // 2 M-waves x 4 N-waves, 64x64 each
    const int fr = lane & 15, g8 = (lane >> 4) << 3, fq = (lane >> 4) << 2;
    const int jq = g8 >> 3;          // logical 16B chunk (0..3)
    const int sx2 = (fr >> 1) & 3;   // read-side XOR

    const int srow = lane >> 2;
    const int scol = ((lane & 3) ^ ((lane >> 3) & 3)) << 3;
    const unsigned short* gA  = A + (size_t)(bm + wave * 16 + srow) * lda + scol + koff;
    const unsigned short* gB0 = Bt + (size_t)(bn + wave * 32 + srow) * ldb + scol + koff;
    const unsigned short* gB1 = gB0 + (size_t)16 * ldb;
    const int lbA = wave * 512;      // wave-uniform LDS bases (shorts)
    const int lbB = wave * 1024;

    f32x4 acc[4][4];
    #pragma unroll
    for (int m = 0; m < 4; ++m)
        #pragma unroll
        for (int n_ = 0; n_ < 4; ++n_)
            #pragma unroll
            for (int r_ = 0; r_ < 4; ++r_) acc[m][n_][r_] = 0.0f;

    auto stage = [&](int buf, int k0) {
        gld_lds16(gA + k0, &As[buf][lbA]);
        gld_lds16(gB0 + k0, &Bs[buf][lbB]);
        gld_lds16(gB1 + k0, &Bs[buf][lbB + 512]);
    };
    auto compute = [&](int buf) {
        half8 af[4], bfv[4];
        #pragma unroll
        for (int m = 0; m < 4; ++m)
            af[m] = *reinterpret_cast<const half8*>(
                &As[buf][(wm * 64 + m * 16 + fr) * 32 + ((jq ^ sx2) << 3)]);
        #pragma unroll
        for (int n_ = 0; n_ < 4; ++n_)
            bfv[n_] = *reinterpret_cast<const half8*>(
                &Bs[buf][(wn * 64 + n_ * 16 + fr) * 32 + ((jq ^ sx2) << 3)]);
        #pragma unroll
        for (int m = 0; m < 4; ++m)
            #pragma unroll
            for (int n_ = 0; n_ < 4; ++n_)
                acc[m][n_] = __builtin_amdgcn_mfma_f32_16x16x32_f16(af[m], bfv[n_], acc[m][n_], 0, 0, 0);
    };

    const int nt = K >> 5;   // even for all our shapes
    stage(0, 0);
    __syncthreads();
    int k0 = 32;
    for (int t = 0; t < nt - 2; t += 2) {
        stage(1, k0);
        compute(0);
        __syncthreads();
        stage(0, k0 + 32);
        compute(1);
        __syncthreads();
        k0 += 64;
    }
    stage(1, k0);
    compute(0);
    __syncthreads();
    compute(1);

    if (EPI == 4) {
        unsigned short* P = reinterpret_cast<unsigned short*>(Cout) +
                            (size_t)z * (size_t)M * ldc;
        #pragma unroll
        for (int n_ = 0; n_ < 4; ++n_) {
            const int col = bn + wn * 64 + n_ * 16 + fr;
            #pragma unroll
            for (int m = 0; m < 4; ++m)
                #pragma unroll
                for (int r_ = 0; r_ < 4; ++r_) {
                    const int row = bm + wm * 64 + m * 16 + fq + r_;
                    P[(size_t)row * ldc + col] = f2h(acc[m][n_][r_]);
                }
        }
        return;
    }

    unsigned short* o16 = reinterpret_cast<unsigned short*>(Cout);
    #pragma unroll
    for (int n_ = 0; n_ < 4; ++n_) {
        const int col = bn + wn * 64 + n_ * 16 + fr;
        const float bc = bias[col];
        #pragma unroll
        for (int m = 0; m < 4; ++m) {
            #pragma unroll
            for (int r_ = 0; r_ < 4; ++r_) {
                const int row = bm + wm * 64 + m * 16 + fq + r_;
                const size_t idx = (size_t)row * ldc + col;
                float v = acc[m][n_][r_] + bc;
                if (EPI == 0) {
                    o16[idx] = f2h(v);
                } else {
                    o16[idx] = f2h(gelu_fast(v));
                }
            }
        }
    }
}

// ---------------- 2-phase GEMM (skinny shapes), BK=32 chunk-swizzle -----------------
// REMAP=1: 1-D grid, xcd = bid&7 == bm%8, bn fastest within XCD.
// EPI 5: fp16 = acc + bias + resid(f32)   (x1h residual-out for proj)
template<int EPI, int BM, int REMAP>
__global__ __launch_bounds__(256)
void gemm_bt(const unsigned short* __restrict__ A, const unsigned short* __restrict__ Bt,
             const float* __restrict__ bias, const float* resid,
             void* Cout, int M, int N, int K, int lda, int ldb, int ldc) {
    constexpr int MF = BM / 32;
    __shared__ unsigned short As[2][BM * 32];
    __shared__ unsigned short Bs[2][128 * 32];
    const int tid = threadIdx.x;
    const int wave = tid >> 6, lane = tid & 63;
    int bm, bn;
    if (REMAP) {
        const int nxr = N >> 7;
        int bid = blockIdx.x;
        const int xcd = bid & 7; int rest = bid >> 3;
        bn = (rest % nxr) << 7; rest /= nxr;
        bm = (rest * 8 + xcd) * BM;              // requires (M/BM) % 8 == 0
    } else {
        bm = blockIdx.y * BM; bn = blockIdx.x << 7;
    }
    const int wr = (wave >> 1) * (BM / 2), wc = (wave & 1) << 6;
    const int fr = lane & 15, g8 = (lane >> 4) << 3, fq = (lane >> 4) << 2;
    const int jq = g8 >> 3, sx2 = (fr >> 1) & 3;

    const int srowA = (BM == 128) ? ((wave << 5) + (lane >> 2)) : ((wave << 4) + (lane >> 2));
    const int srowB = (wave << 5) + (lane >> 2);
    const int scol = (((lane & 3) ^ ((lane >> 3) & 3))) << 3;
    const unsigned short* gA0 = A + (size_t)(bm + srowA) * lda + scol;
    const unsigned short* gA1 = gA0 + (size_t)16 * lda;      // BM==128 only
    const unsigned short* gB0 = Bt + (size_t)(bn + srowB) * ldb + scol;
    const unsigned short* gB1 = gB0 + (size_t)16 * ldb;

    f32x4 acc[MF][4];
    #pragma unroll
    for (int m = 0; m < MF; ++m)
        #pragma unroll
        for (int n = 0; n < 4; ++n)
            #pragma unroll
            for (int r = 0; r < 4; ++r) acc[m][n][r] = 0.0f;

    auto stage = [&](int buf, int k0) {
        unsigned short* lA = &As[buf][(BM == 128) ? (wave << 10) : (wave << 9)];
        unsigned short* lB = &Bs[buf][wave << 10];
        gld_lds16(gA0 + k0, lA);
        if constexpr (BM == 128) gld_lds16(gA1 + k0, lA + 512);
        gld_lds16(gB0 + k0, lB);
        gld_lds16(gB1 + k0, lB + 512);
    };
    auto compute = [&](int buf) {
        half8 af[MF], bfv[4];
        #pragma unroll
        for (int m = 0; m < MF; ++m)
            af[m] = *reinterpret_cast<const half8*>(
                &As[buf][(wr + m * 16 + fr) * 32 + ((jq ^ sx2) << 3)]);
        #pragma unroll
        for (int n = 0; n < 4; ++n)
            bfv[n] = *reinterpret_cast<const half8*>(
                &Bs[buf][(wc + n * 16 + fr) * 32 + ((jq ^ sx2) << 3)]);
        #pragma unroll
        for (int m = 0; m < MF; ++m)
            #pragma unroll
            for (int n = 0; n < 4; ++n)
                acc[m][n] = __builtin_amdgcn_mfma_f32_16x16x32_f16(af[m], bfv[n], acc[m][n], 0, 0, 0);
    };

    const int nt = K >> 5;
    stage(0, 0);
    __syncthreads();
    int k0 = 32;
    for (int t = 0; t < nt - 2; t += 2) {
        stage(1, k0);
        compute(0);
        __syncthreads();
        stage(0, k0 + 32);
        compute(1);
        __syncthreads();
        k0 += 64;
    }
    stage(1, k0);
    compute(0);
    __syncthreads();
    compute(1);

    #pragma unroll
    for (int n = 0; n < 4; ++n) {
        const int col = bn + wc + n * 16 + fr;
        const float bc = bias[col];
        #pragma unroll
        for (int m = 0; m < MF; ++m) {
            #pragma unroll
            for (int r = 0; r < 4; ++r) {
                const int row = bm + wr + m * 16 + fq + r;
                const size_t idx = (size_t)row * ldc + col;
                float v = acc[m][n][r] + bc;
                // EPI 5: fp16 residual-out
                reinterpret_cast<unsigned short*>(Cout)[idx] = f2h(v + resid[idx]);
            }
        }
    }
}

// ---------------- split-K reduce: out(f32) = x1h(fp16) + bias + sum_z p[z](fp16) ----
template<int Z>
__global__ __launch_bounds__(256)
void red_h(const unsigned short* __restrict__ p, const unsigned short* __restrict__ x1h,
           const float* __restrict__ bias, float* out) {
    const size_t MN = (size_t)4096 * 1024;
    const size_t i = ((size_t)blockIdx.x * 256 + threadIdx.x) * 4;
    ushort4 xh = *reinterpret_cast<const ushort4*>(x1h + i);
    float4 bb = *reinterpret_cast<const float4*>(bias + (i & 1023));
    float o0 = h2f(xh.x) + bb.x, o1 = h2f(xh.y) + bb.y;
    float o2 = h2f(xh.z) + bb.z, o3 = h2f(xh.w) + bb.w;
    #pragma unroll
    for (int z = 0; z < Z; ++z) {
        ushort4 a = *reinterpret_cast<const ushort4*>(p + (size_t)z * MN + i);
        o0 += h2f(a.x); o1 += h2f(a.y); o2 += h2f(a.z); o3 += h2f(a.w);
    }
    float4 o; o.x = o0; o.y = o1; o.z = o2; o.w = o3;
    *reinterpret_cast<float4*>(out + i) = o;
}

// ---------------- K/V compaction ----------------
// K scaled by 8*log2(e): P = exp2(S - m) == exp((q.k)*8 - m'), one mul cheaper.
__global__ __launch_bounds__(256)
void kv_conv(const unsigned short* __restrict__ qkv16, unsigned short* __restrict__ K_g,
             unsigned short* __restrict__ Vt_g) {
    __shared__ unsigned short VtT[64][72];
    const int kc = blockIdx.x;
    const int bh = blockIdx.y;
    const int b = bh >> 4, h = bh & 15;
    const int tid = threadIdx.x;
    const int key = tid >> 2, c16 = (tid & 3) << 4;
    const unsigned short* kp = qkv16 + ((size_t)(b * 1024 + kc * 64 + key)) * 3072 + 1024 + h * 64 + c16;
    alignas(16) unsigned short kbuf[16];
    const float KSCALE = 8.0f * 1.44269504088896f;   // 8 * log2(e)
    #pragma unroll
    for (int j = 0; j < 16; j += 8) {
        short8 k8 = *reinterpret_cast<const short8*>(kp + j);
        short8 v8 = *reinterpret_cast<const short8*>(kp + 1024 + j);
        #pragma unroll
        for (int c = 0; c < 8; ++c) {
            kbuf[j + c] = f2h(KSCALE * h2f((unsigned short)k8[c]));
            VtT[c16 + j + c][key] = (unsigned short)v8[c];
        }
    }
    const size_t kb = ((size_t)bh * 1024 + kc * 64 + key) * 64 + c16;
    *reinterpret_cast<short8*>(K_g + kb)     = *reinterpret_cast<short8*>(&kbuf[0]);
    *reinterpret_cast<short8*>(K_g + kb + 8) = *reinterpret_cast<short8*>(&kbuf[8]);
    __syncthreads();
    const int d = tid >> 2;
    const size_t vb = ((size_t)bh * 64 + d) * 1024 + (size_t)kc * 64 + c16;
    *reinterpret_cast<short8*>(Vt_g + vb)     = *reinterpret_cast<const short8*>(&VtT[d][c16]);
    *reinterpret_cast<short8*>(Vt_g + vb + 8) = *reinterpret_cast<const short8*>(&VtT[d][c16 + 8]);
}

// ---------------- Flash attention (fp16, QBLK=64, exp2 + ones-MFMA + defer-max) -----
// grid: x = bh (64), y = qt (16) -> all qt-sharers of a head on ONE XCD (bh%8).
// LDS-staged K/V (latency amortization) + T14 register prefetch of next tile.
__global__ __launch_bounds__(256)
void attn_kernel(const unsigned short* __restrict__ qkv16,
                 const unsigned short* __restrict__ K_g,
                 const unsigned short* __restrict__ Vt_g,
                 unsigned short* __restrict__ ctx) {
    __shared__ unsigned short Kh[64][72];
    __shared__ unsigned short Vt[64][72];
    __shared__ unsigned short Plds[4][16][72];
    const int bh = blockIdx.x;          // head-major: co-XCD K/V sharing
    const int qt = blockIdx.y;
    const int b = bh >> 4, h = bh & 15;
    const int tid = threadIdx.x;
    const int wave = tid >> 6, lane = tid & 63;
    const int fr = lane & 15, g8 = (lane >> 4) << 3, fq = (lane >> 4) << 2;

    const int qrow = qt * 64 + wave * 16 + fr;
    const unsigned short* qp = qkv16 + ((size_t)(b * 1024 + qrow)) * 3072 + h * 64;
    half8 qf[2];
    qf[0] = *reinterpret_cast<const half8*>(qp + g8);
    qf[1] = *reinterpret_cast<const half8*>(qp + 32 + g8);

    half8 ones;
    #pragma unroll
    for (int j = 0; j < 8; ++j) ones[j] = (_Float16)1.0f;

    float mrun[4];
    f32x4 cacc[4], csum;
    #pragma unroll
    for (int r = 0; r < 4; ++r) { mrun[r] = -3.0e38f; csum[r] = 0.0f; }
    #pragma unroll
    for (int nd = 0; nd < 4; ++nd)
        #pragma unroll
        for (int r = 0; r < 4; ++r) cacc[nd][r] = 0.0f;

    const int skey = tid >> 2, sc16 = (tid & 3) << 4;
    const unsigned short* kgp = K_g + ((size_t)bh * 1024 + skey) * 64 + sc16;
    const unsigned short* vgp = Vt_g + ((size_t)bh * 64 + skey) * 1024 + sc16;

    short8 ka = *reinterpret_cast<const short8*>(kgp);
    short8 kb = *reinterpret_cast<const short8*>(kgp + 8);
    short8 va = *reinterpret_cast<const short8*>(vgp);
    short8 vb = *reinterpret_cast<const short8*>(vgp + 8);

    for (int kt = 0; kt < 16; ++kt) {
        __syncthreads();
        *reinterpret_cast<short8*>(&Kh[skey][sc16])     = ka;
        *reinterpret_cast<short8*>(&Kh[skey][sc16 + 8]) = kb;
        *reinterpret_cast<short8*>(&Vt[skey][sc16])     = va;
        *reinterpret_cast<short8*>(&Vt[skey][sc16 + 8]) = vb;
        __syncthreads();
        // T14: issue next tile's loads; hide under compute
        const int ktn = (kt < 15) ? kt + 1 : 15;
        ka = *reinterpret_cast<const short8*>(kgp + (size_t)ktn * 4096);
        kb = *reinterpret_cast<const short8*>(kgp + (size_t)ktn * 4096 + 8);
        va = *reinterpret_cast<const short8*>(vgp + ktn * 64);
        vb = *reinterpret_cast<const short8*>(vgp + ktn * 64 + 8);

        f32x4 S[4];
        #pragma unroll
        for (int n = 0; n < 4; ++n)
            #pragma unroll
            for (int r = 0; r < 4; ++r) S[n][r] = 0.0f;
        #pragma unroll
        for (int s_ = 0; s_ < 2; ++s_)
            #pragma unroll
            for (int n = 0; n < 4; ++n) {
                half8 kh = *reinterpret_cast<const half8*>(&Kh[n * 16 + fr][s_ * 32 + g8]);
                S[n] = __builtin_amdgcn_mfma_f32_16x16x32_f16(qf[s_], kh, S[n], 0, 0, 0);
            }

        // row max over 16 lanes (4 shuffle rounds)
        float mt[4];
        #pragma unroll
        for (int r = 0; r < 4; ++r)
            mt[r] = fmaxf(fmaxf(S[0][r], S[1][r]), fmaxf(S[2][r], S[3][r]));
        #pragma unroll
        for (int r = 0; r < 4; ++r) {
            mt[r] = fmaxf(mt[r], __shfl_xor(mt[r], 1));
            mt[r] = fmaxf(mt[r], __shfl_xor(mt[r], 2));
            mt[r] = fmaxf(mt[r], __shfl_xor(mt[r], 4));
            mt[r] = fmaxf(mt[r], __shfl_xor(mt[r], 8));
        }
        // defer-max: rescale only when any row max grew > 8 (wave-uniform)
        int grow = 0;
        #pragma unroll
        for (int r = 0; r < 4; ++r) grow |= (mt[r] > mrun[r] + 8.0f) ? 1 : 0;
        if (__any(grow)) {
            #pragma unroll
            for (int r = 0; r < 4; ++r) {
                float mnew = fmaxf(mrun[r], mt[r]);
                float sf = __builtin_amdgcn_exp2f(mrun[r] - mnew);
                mrun[r] = mnew;
                csum[r] *= sf;
                #pragma unroll
                for (int nd = 0; nd < 4; ++nd) cacc[nd][r] *= sf;
            }
        }
        // P = exp2(S - m), bounded by 2^8; per-wave LDS slab (same-wave RAW)
        #pragma unroll
        for (int r = 0; r < 4; ++r)
            #pragma unroll
            for (int n = 0; n < 4; ++n)
                Plds[wave][fq + r][n * 16 + fr] =
                    f2h(__builtin_amdgcn_exp2f(S[n][r] - mrun[r]));
        #pragma unroll
        for (int s_ = 0; s_ < 2; ++s_) {
            half8 pa = *reinterpret_cast<const half8*>(&Plds[wave][fr][s_ * 32 + g8]);
            #pragma unroll
            for (int nd = 0; nd < 4; ++nd) {
                half8 vb8 = *reinterpret_cast<const half8*>(&Vt[nd * 16 + fr][s_ * 32 + g8]);
                cacc[nd] = __builtin_amdgcn_mfma_f32_16x16x32_f16(pa, vb8, cacc[nd], 0, 0, 0);
            }
            csum = __builtin_amdgcn_mfma_f32_16x16x32_f16(pa, ones, csum, 0, 0, 0);
        }
    }
    #pragma unroll
    for (int r = 0; r < 4; ++r) {
        const float inv = 1.0f / csum[r];
        const int row = qt * 64 + wave * 16 + fq + r;
        unsigned short* cp = ctx + ((size_t)(b * 1024 + row)) * 1024 + h * 64;
        #pragma unroll
        for (int nd = 0; nd < 4; ++nd)
            cp[nd * 16 + fr] = f2h(cacc[nd][r] * inv);
    }
}

// ---------------- launch ----------------
extern "C" void kernel_launch(void* const* d_in, const int* in_sizes, int n_in,
                              void* d_out, int out_size, void* d_ws, size_t ws_size,
                              hipStream_t stream) {
    const float* x      = (const float*)d_in[0];
    const float* norm_g = (const float*)d_in[1];
    const float* norm_b = (const float*)d_in[2];
    const float* w_qkv  = (const float*)d_in[3];
    const float* b_qkv  = (const float*)d_in[4];
    const float* w_proj = (const float*)d_in[5];
    const float* b_proj = (const float*)d_in[6];
    const float* w_fc1  = (const float*)d_in[7];
    const float* b_fc1  = (const float*)d_in[8];
    const float* w_fc2  = (const float*)d_in[9];
    const float* b_fc2  = (const float*)d_in[10];
    float* out = (float*)d_out;
    char* ws = (char*)d_ws;

    size_t off = 0;
    unsigned short* wqkvT  = (unsigned short*)(ws + off); off += (size_t)3072 * 1024 * 2;
    unsigned short* wprojT = (unsigned short*)(ws + off); off += (size_t)1024 * 1024 * 2;
    unsigned short* wfc1T  = (unsigned short*)(ws + off); off += (size_t)4096 * 1024 * 2;
    unsigned short* wfc2T  = (unsigned short*)(ws + off); off += (size_t)1024 * 4096 * 2;
    unsigned short* ctxb   = (unsigned short*)(ws + off); off += (size_t)4096 * 1024 * 2;
    char* G = ws + off;
    // G region timeline (byte offsets; watermark identical to rounds 16/18):
    //   h1     ( 8.4 MB) at G+0         : prep -> qkv GEMM
    //   qkv16  (25.2 MB) at G+8388608   : qkv GEMM -> attn (q) / kv_conv
    //   K_g    ( 8.4 MB) at G+0         : kv_conv -> attn (overlaps dead h1)
    //   Vt_g   ( 8.4 MB) at G+33554432  : kv_conv -> attn
    //   fc1o   (33.5 MB) at G+0         : fc1 -> fc2
    //   h2     ( 8.4 MB) at G+41943040  : ln2 -> fc1 (dead before fc2)
    //   fc2ph  [4][4096][1024] fp16 (33.5 MB) at G+33554432 : fc2 partials -> red
    //   x1h    ( 8.4 MB) at G+67108864  : proj -> ln2/red (fp16 residual)
    unsigned short* h1    = (unsigned short*)G;
    unsigned short* qkv16 = (unsigned short*)(G + (size_t)8388608);
    unsigned short* K_g   = (unsigned short*)G;
    unsigned short* Vt_g  = (unsigned short*)(G + (size_t)33554432);
    unsigned short* fc1o  = (unsigned short*)G;
    unsigned short* h2    = (unsigned short*)(G + (size_t)41943040);
    unsigned short* fc2ph = (unsigned short*)(G + (size_t)33554432);
    unsigned short* x1h   = (unsigned short*)(G + (size_t)67108864);

    // fused prep: weight transposes + h1 = LN(x), one launch
    prep_fused<<<16384, 256, 0, stream>>>(w_qkv, w_proj, w_fc1, w_fc2,
                                          wqkvT, wprojT, wfc1T, wfc2T,
                                          x, norm_g, norm_b, h1);

    // qkv16 = fp16(h1 @ w_qkv + b)   (gemm_mid: 384 blocks)
    gemm_mid<0, 1><<<384, 512, 0, stream>>>(h1, wqkvT, b_qkv, qkv16,
                                            4096, 3072, 1024, 1024, 1024, 3072);

    // compact K (x 8*log2e) and V^T
    kv_conv<<<dim3(16, 64), 256, 0, stream>>>(qkv16, K_g, Vt_g);

    // attention -> ctx (fp16); head-major grid for XCD-local K/V
    attn_kernel<<<dim3(64, 16), 256, 0, stream>>>(qkv16, K_g, Vt_g, ctxb);

    // x1h = fp16(x + ctx @ w_proj + b)   (2-phase BM=64 + XCD remap)
    gemm_bt<5, 64, 1><<<512, 256, 0, stream>>>(ctxb, wprojT, b_proj, x, x1h,
                                               4096, 1024, 1024, 1024, 1024, 1024);

    // h2 = LN(x1h) ; fc1 = gelu_fast(h2 @ w_fc1 + b)   (gemm_mid: 512 blocks = 2/CU)
    ln16_kernel<<<4096, 256, 0, stream>>>(x1h, norm_g, norm_b, h2);
    gemm_mid<2, 1><<<512, 512, 0, stream>>>(h2, wfc1T, b_fc1, fc1o,
                                            4096, 4096, 1024, 1024, 1024, 4096);

    // fc2: gemm_mid split-K=4 (512 blocks = 2/CU), XCD-local A-tiles, fp16 partials
    gemm_mid<4, 4><<<512, 512, 0, stream>>>(fc1o, wfc2T, nullptr, fc2ph,
                                            4096, 1024, 1024, 4096, 4096, 1024);
    // out(f32) = x1h + b_fc2 + sum partials
    red_h<4><<<4096, 256, 0, stream>>>(fc2ph, x1h, b_fc2, out);
}